// Round 10
// baseline (81.731 us; speedup 1.0000x reference)
//
#include <hip/hip_runtime.h>
#include <hip/hip_bf16.h>

#define NXX 256
#define NG 32768
#define WID 128
#define STRW 68   // LDS row stride in u32 words (odd*4: aligned b128, spread banks)

typedef short bf16x8 __attribute__((ext_vector_type(8)));
typedef float f32x4 __attribute__((ext_vector_type(4)));
typedef float f32x2 __attribute__((ext_vector_type(2)));

__device__ __forceinline__ unsigned short rne_bf16(float x) {
    unsigned int u = __float_as_uint(x);
    return (unsigned short)((u + 0x7fffu + ((u >> 16) & 1u)) >> 16);
}

// ---------------------------------------------------------------------------
// Prep: pack Wg (4 layers of [128 k][128 n] fp32) into fragment-linear bf16
// streams. Lane l of stream e=(l*4+kc)*8+nt holds W[kc*32+(l>>4)*8+j][nt*16+(l&15)].
// Used as the *A* operand of mfma (W^T tile).
// ---------------------------------------------------------------------------
__global__ __launch_bounds__(64) void prep_kernel(
    const float* __restrict__ Wg, unsigned short* __restrict__ Bfrag) {
    const int e  = blockIdx.x;       // 0..127
    const int lv = threadIdx.x;      // 0..63
    const int l  = e >> 5;
    const int kc = (e >> 3) & 3;
    const int nt = e & 7;
    const int n  = nt * 16 + (lv & 15);
    const int kb = kc * 32 + ((lv >> 4) << 3);
#pragma unroll
    for (int j = 0; j < 8; ++j) {
        float v = Wg[(size_t)l * 16384 + (size_t)(kb + j) * WID + n];
        Bfrag[(size_t)e * 512 + lv * 8 + j] = rne_bf16(v);
    }
}

__device__ __forceinline__ unsigned int pack_bf2(float a, float b) {
    union { __hip_bfloat162 h2; unsigned int u; } cv;
    cv.h2 = __float22bfloat162_rn(make_float2(a, b));   // low16 = a (even col)
    return cv.u;
}

// ---------------------------------------------------------------------------
// Fused net (r9 structure). Each wave owns 16 NODES (u = ublk+16w+(lane&15)),
// computes TWO MFMA tiles per layer (batch b and b+2) -> pair-mix is
// register-local. LDS round-trip for B-frag relayout, barrier-free.
// NEW (r10): all elementwise phases (X0 build, mix, LN, residual, head) are
// written as float2 ext-vector math so the compiler emits CDNA packed-fp32
// VOP3P (v_pk_fma_f32 / v_pk_add_f32 / v_pk_mul_f32 / v_pk_max_f32),
// ~halving the VALU instruction count — VALU issue (~26us) is the floor.
// ---------------------------------------------------------------------------
__global__ __launch_bounds__(256) void fused_kernel(
    const float* __restrict__ u0, const float* __restrict__ P,
    const float* __restrict__ W_in, const float* __restrict__ b_in,
    const unsigned short* __restrict__ Bfrag,
    const float* __restrict__ bg, const float* __restrict__ gamma,
    const float* __restrict__ beta, const float* __restrict__ W_out,
    const float* __restrict__ b_out, float* __restrict__ out)
{
    __shared__ unsigned int XsH[8][16 * STRW];   // 34816 B

    const int tid  = threadIdx.x;
    const int w    = tid >> 6;
    const int lane = tid & 63;
    const int l15  = lane & 15;
    const int lhi  = lane >> 4;      // 0..3

    const int blk  = blockIdx.x;     // 0..1023
    const int b    = blk >> 9;       // 0 or 1; partner batch = b+2
    const int ublk = (blk & 511) << 6;

    const int u  = ublk + 16 * w + l15;
    const int ix = u >> 7;
    const int t  = u & 127;

    // degree coeffs (t-major graph indexing), per-lane
    float c1, c2;
    {
        int gi = u & 255, gt = u >> 8;
        int d  = (gi > 0) + (gi < 255) + (gt > 0) + (gt < 127);
        float deg = 2.f * (float)d + 1.f;
        c1 = 2.f * (float)d * rsqrtf(deg);
        c2 = 1.f / deg;
    }

    // ---- features of node u for batch b (A) and b+2 (B) ----
    float featA[7], featB[7];
    {
        float s  = ((float)t + 0.5f) * 0.125f - 0.5f;
        float fs = floorf(s);
        int   t0 = (int)fs;
        float wt = s - fs;
        int t0c = t0 < 0 ? 0 : (t0 > 15 ? 15 : t0);
        int t1n = t0 + 1;
        int t1c = t1n < 0 ? 0 : (t1n > 15 ? 15 : t1n);
        const float* urA = u0 + ((size_t)b * NXX + ix) * 16;
        const float* urB = u0 + ((size_t)(b + 2) * NXX + ix) * 16;
        featA[0] = urA[t0c] * (1.f - wt) + urA[t1c] * wt;
        featB[0] = urB[t0c] * (1.f - wt) + urB[t1c] * wt;
#pragma unroll
        for (int f = 0; f < 4; ++f) {
            featA[1 + f] = P[b * 4 + f];
            featB[1 + f] = P[(b + 2) * 4 + f];
        }
        featA[5] = featB[5] = (float)ix * (1.f / 255.f);
        featA[6] = featB[6] = (float)t  * (1.f / 127.f);
    }

    // ---- X0 = feat @ W_in + b_in for both tiles (packed-f32 math) ----
    f32x2 xr0[8][2], xr1[8][2];
    {
        f32x2 FA[7], FB[7];
#pragma unroll
        for (int f = 0; f < 7; ++f) {
            FA[f] = (f32x2){featA[f], featA[f]};
            FB[f] = (f32x2){featB[f], featB[f]};
        }
#pragma unroll
        for (int nt = 0; nt < 8; ++nt) {
            const int c = nt * 16 + 4 * lhi;
            float4 bi4 = *(const float4*)(b_in + c);
            float4 wf[7];
#pragma unroll
            for (int f = 0; f < 7; ++f) wf[f] = *(const float4*)(W_in + f * WID + c);
            const float* bp = (const float*)&bi4;
#pragma unroll
            for (int h = 0; h < 2; ++h) {
                f32x2 a0 = (f32x2){bp[2 * h], bp[2 * h + 1]};
                f32x2 a1 = a0;
#pragma unroll
                for (int f = 0; f < 7; ++f) {
                    const float* wp = (const float*)&wf[f];
                    f32x2 W2 = (f32x2){wp[2 * h], wp[2 * h + 1]};
                    a0 = a0 + FA[f] * W2;
                    a1 = a1 + FB[f] * W2;
                }
                xr0[nt][h] = a0;
                xr1[nt][h] = a1;
            }
        }
    }

    unsigned int* Hrow0 = &XsH[2 * w][l15 * STRW];
    unsigned int* Hrow1 = &XsH[2 * w + 1][l15 * STRW];

    const f32x2 C1 = (f32x2){c1, c1};
    const f32x2 C2 = (f32x2){c2, c2};
    const f32x2 Z2 = (f32x2){0.f, 0.f};

    // ======== 4 GCN layers (barrier-free) ========
    for (int l = 0; l < 4; ++l) {
        // ---- pack bf16 and store both tiles (one b64 per nt per tile) ----
#pragma unroll
        for (int nt = 0; nt < 8; ++nt) {
            unsigned int p0 = pack_bf2(xr0[nt][0][0], xr0[nt][0][1]);
            unsigned int p1 = pack_bf2(xr0[nt][1][0], xr0[nt][1][1]);
            *(uint2*)(Hrow0 + 8 * nt + 2 * lhi) = make_uint2(p0, p1);
            unsigned int q0 = pack_bf2(xr1[nt][0][0], xr1[nt][0][1]);
            unsigned int q1 = pack_bf2(xr1[nt][1][0], xr1[nt][1][1]);
            *(uint2*)(Hrow1 + 8 * nt + 2 * lhi) = make_uint2(q0, q1);
        }

        // ---- read X fragments (B-operand layout: row l15, k = 32kc+8lhi+j) --
        bf16x8 xh0[4], xh1[4];
#pragma unroll
        for (int kc = 0; kc < 4; ++kc) {
            xh0[kc] = *(const bf16x8*)(Hrow0 + 16 * kc + 4 * lhi);
            xh1[kc] = *(const bf16x8*)(Hrow1 + 16 * kc + 4 * lhi);
        }

        // ---- MFMA both tiles, sharing each bh load ----
        f32x4 acc0[8], acc1[8];
        const unsigned short* bp = Bfrag + (size_t)l * 16384 + lane * 8;
#pragma unroll
        for (int nt = 0; nt < 8; ++nt) {
            f32x4 a0 = {0.f, 0.f, 0.f, 0.f};
            f32x4 a1 = {0.f, 0.f, 0.f, 0.f};
#pragma unroll
            for (int kc = 0; kc < 4; ++kc) {
                bf16x8 bh = *(const bf16x8*)(bp + (kc * 8 + nt) * 512);
                a0 = __builtin_amdgcn_mfma_f32_16x16x32_bf16(bh, xh0[kc], a0, 0, 0, 0);
                a1 = __builtin_amdgcn_mfma_f32_16x16x32_bf16(bh, xh1[kc], a1, 0, 0, 0);
            }
            acc0[nt] = a0;
            acc1[nt] = a1;
        }

        // ---- epilogue (packed-f32): mix in place, accumulate LN sums ----
        f32x2 s0 = Z2, q0 = Z2, s1 = Z2, q1 = Z2;
#pragma unroll
        for (int nt = 0; nt < 8; ++nt) {
            float4 bg4 = *(const float4*)(bg + l * WID + nt * 16 + 4 * lhi);
            const float* bgp = (const float*)&bg4;
#pragma unroll
            for (int h = 0; h < 2; ++h) {
                f32x2 BG = (f32x2){bgp[2 * h], bgp[2 * h + 1]};
                f32x2 H0 = (f32x2){acc0[nt][2 * h], acc0[nt][2 * h + 1]};
                f32x2 H1 = (f32x2){acc1[nt][2 * h], acc1[nt][2 * h + 1]};
                f32x2 A0 = H0 + BG;                      // batch b (deg 1)
                f32x2 A1 = C1 * H0 + (C2 * H1 + BG);     // batch b+2
                acc0[nt][2 * h] = A0[0]; acc0[nt][2 * h + 1] = A0[1];
                acc1[nt][2 * h] = A1[0]; acc1[nt][2 * h + 1] = A1[1];
                s0 = s0 + A0;  q0 = q0 + A0 * A0;
                s1 = s1 + A1;  q1 = q1 + A1 * A1;
            }
        }
        float S0 = s0[0] + s0[1], Q0 = q0[0] + q0[1];
        float S1 = s1[0] + s1[1], Q1 = q1[0] + q1[1];
        S0 += __shfl_xor(S0, 16);  Q0 += __shfl_xor(Q0, 16);
        S1 += __shfl_xor(S1, 16);  Q1 += __shfl_xor(Q1, 16);
        S0 += __shfl_xor(S0, 32);  Q0 += __shfl_xor(Q0, 32);
        S1 += __shfl_xor(S1, 32);  Q1 += __shfl_xor(Q1, 32);
        float mu0 = S0 * (1.f / 128.f);
        float mu1 = S1 * (1.f / 128.f);
        float rs0 = rsqrtf(Q0 * (1.f / 128.f) - mu0 * mu0 + 1e-5f);
        float rs1 = rsqrtf(Q1 * (1.f / 128.f) - mu1 * mu1 + 1e-5f);
        // LN apply: (a-mu)*rs*g + e  ==  (a*rs - mu*rs)*g + e  (2 pk_fma)
        const f32x2 RS0 = (f32x2){rs0, rs0};
        const f32x2 RS1 = (f32x2){rs1, rs1};
        const f32x2 MR0 = (f32x2){-mu0 * rs0, -mu0 * rs0};
        const f32x2 MR1 = (f32x2){-mu1 * rs1, -mu1 * rs1};
#pragma unroll
        for (int nt = 0; nt < 8; ++nt) {
            const int c = nt * 16 + 4 * lhi;
            float4 g4 = *(const float4*)(gamma + l * WID + c);
            float4 e4 = *(const float4*)(beta  + l * WID + c);
            const float* gp = (const float*)&g4;
            const float* ep = (const float*)&e4;
#pragma unroll
            for (int h = 0; h < 2; ++h) {
                f32x2 G = (f32x2){gp[2 * h], gp[2 * h + 1]};
                f32x2 E = (f32x2){ep[2 * h], ep[2 * h + 1]};
                f32x2 A0 = (f32x2){acc0[nt][2 * h], acc0[nt][2 * h + 1]};
                f32x2 A1 = (f32x2){acc1[nt][2 * h], acc1[nt][2 * h + 1]};
                f32x2 T0 = A0 * RS0 + MR0;
                f32x2 T1 = A1 * RS1 + MR1;
                T0 = T0 * G + E;
                T1 = T1 * G + E;
                T0 = T0 + xr0[nt][h];
                T1 = T1 + xr1[nt][h];
                xr0[nt][h] = __builtin_elementwise_max(T0, Z2);
                xr1[nt][h] = __builtin_elementwise_max(T1, Z2);
            }
        }
        // no barrier: wave-private LDS slices; within-wave DS deps order them.
    }

    // ======== out head: two rows per lane (packed-f32) ========
    f32x2 P0 = Z2, P1 = Z2;
#pragma unroll
    for (int nt = 0; nt < 8; ++nt) {
        float4 wo4 = *(const float4*)(W_out + nt * 16 + 4 * lhi);
        const float* wp = (const float*)&wo4;
#pragma unroll
        for (int h = 0; h < 2; ++h) {
            f32x2 W2 = (f32x2){wp[2 * h], wp[2 * h + 1]};
            P0 = P0 + xr0[nt][h] * W2;
            P1 = P1 + xr1[nt][h] * W2;
        }
    }
    float p0 = P0[0] + P0[1];
    float p1 = P1[0] + P1[1];
    p0 += __shfl_xor(p0, 16);  p1 += __shfl_xor(p1, 16);
    p0 += __shfl_xor(p0, 32);  p1 += __shfl_xor(p1, 32);
    if (lhi == 0) {
        float bo = b_out[0];
        out[(size_t)b * NG + u]       = p0 + bo;
        out[(size_t)(b + 2) * NG + u] = p1 + bo;
    }
}

// ---------------------------------------------------------------------------
extern "C" void kernel_launch(void* const* d_in, const int* in_sizes, int n_in,
                              void* d_out, int out_size, void* d_ws, size_t ws_size,
                              hipStream_t stream) {
    const float* u0    = (const float*)d_in[0];
    const float* P     = (const float*)d_in[1];
    const float* W_in  = (const float*)d_in[2];
    const float* b_in  = (const float*)d_in[3];
    const float* Wg    = (const float*)d_in[4];
    const float* bg    = (const float*)d_in[5];
    const float* gamma = (const float*)d_in[6];
    const float* beta  = (const float*)d_in[7];
    const float* W_out = (const float*)d_in[8];
    const float* b_out = (const float*)d_in[9];

    unsigned short* Bfrag = (unsigned short*)d_ws;   // 128 KB

    prep_kernel<<<128, 64, 0, stream>>>(Wg, Bfrag);
    fused_kernel<<<1024, 256, 0, stream>>>(
        u0, P, W_in, b_in, Bfrag, bg, gamma, beta, W_out, b_out, (float*)d_out);
}